// Round 13
// baseline (45.980 us; speedup 1.0000x reference)
//
#include <hip/hip_runtime.h>

#define Cc 8
#define Hh 128
#define Ww 128
#define Nn 64
#define Bb 8
#define Dd 169            // (C+2)*C + C + C*C + C + C + 1
#define HW (Hh * Ww)
#define GN 8              // n's per block
#define NGRP (Nn / GN)    // 8
#define PXB 512           // px per block (256 threads x 2 px)
#define CHUNKS (HW / PXB) // 32
#define NBLK (Bb * NGRP * CHUNKS)  // 2048 blocks
#define WSTRIDE 88                 // u32 per bn in packed table (85 used)
#define RED_OFF (Bb * Nn * WSTRIDE)   // float offset of reduction slots in ws
#define SLOTS (NGRP * CHUNKS)         // 256 partial-slots per batch b

#define INV128 (1.0f / 128.0f)

typedef __fp16 f16x2 __attribute__((ext_vector_type(2)));

static __device__ __forceinline__ f16x2 pk(float a, float b) {
    return __builtin_amdgcn_cvt_pkrtz(a, b);   // v_cvt_pkrtz_f16_f32
}
static __device__ __forceinline__ uint32_t pku(float a, float b) {
    f16x2 t = pk(a, b); uint32_t u; __builtin_memcpy(&u, &t, 4); return u;
}
static __device__ __forceinline__ f16x2 max2(f16x2 a, f16x2 b) {
    return __builtin_elementwise_max(a, b);    // v_pk_max_f16
}

// ---- full-rate pk_fma / pk_add with SGPR pair broadcast via op_sel ----
static __device__ __forceinline__ void fma_lo(f16x2& acc, uint32_t w, f16x2 f) {
    asm("v_pk_fma_f16 %0, %1, %2, %0 op_sel:[0,0,0] op_sel_hi:[0,1,1]"
        : "+v"(acc) : "s"(w), "v"(f));
}
static __device__ __forceinline__ void fma_hi(f16x2& acc, uint32_t w, f16x2 f) {
    asm("v_pk_fma_f16 %0, %1, %2, %0 op_sel:[1,0,0] op_sel_hi:[1,1,1]"
        : "+v"(acc) : "s"(w), "v"(f));
}
static __device__ __forceinline__ f16x2 fma_lo4(uint32_t w, f16x2 f, f16x2 c) {
    f16x2 o;
    asm("v_pk_fma_f16 %0, %1, %2, %3 op_sel:[0,0,0] op_sel_hi:[0,1,1]"
        : "=v"(o) : "s"(w), "v"(f), "v"(c));
    return o;
}
// acc += splat(w.lo) / splat(w.hi)  -- bias add, no VGPR needed
static __device__ __forceinline__ void add_lo(f16x2& acc, uint32_t w) {
    asm("v_pk_add_f16 %0, %1, %0 op_sel:[0,0] op_sel_hi:[0,1]"
        : "+v"(acc) : "s"(w));
}
static __device__ __forceinline__ void add_hi(f16x2& acc, uint32_t w) {
    asm("v_pk_add_f16 %0, %1, %0 op_sel:[1,0] op_sel_hi:[1,1]"
        : "+v"(acc) : "s"(w));
}

// ---- kernel A: gather + f16-pack per-bn weight vectors (unchanged r12 layout) ----
// [0..39]=w1 rows (5 pairs/row: (c0,c1)..(c6,c7),(w8,w9)), [40..71]=w2 rows (4/row),
// [72..75]=w3, [76..79]=b1 pairs, [80..83]=b2 pairs, [84]=(b3,0)
__global__ void pack_weights(const float* __restrict__ conv_weight,
                             const int*   __restrict__ ind,
                             uint32_t*    __restrict__ wt) {
    const int bn = blockIdx.x;       // 512
    const int j  = threadIdx.x;      // 96 threads
    const int b  = bn >> 6;
    const int ind_bn = ind[bn];
    const float* src = conv_weight + (size_t)b * Dd * HW + ind_bn;
    if (j < 85) {
        int d0, d1;
        if (j < 40)      { d0 = (j / 5) * 10 + (j % 5) * 2; d1 = d0 + 1; }
        else if (j < 72) { d0 = 88  + 2 * (j - 40); d1 = d0 + 1; }
        else if (j < 76) { d0 = 160 + 2 * (j - 72); d1 = d0 + 1; }
        else if (j < 80) { d0 = 80  + 2 * (j - 76); d1 = d0 + 1; }
        else if (j < 84) { d0 = 152 + 2 * (j - 80); d1 = d0 + 1; }
        else             { d0 = 168; d1 = -1; }
        const float a = src[(size_t)d0 * HW];
        const float c = (d1 >= 0) ? src[(size_t)d1 * HW] : 0.f;
        wt[bn * WSTRIDE + j] = pku(a, c);
    }
}

// ---- kernel B: occupancy-first — 2 px/thread, VGPR<=64 target, 8 waves/EU ----
__global__ __launch_bounds__(256)
__attribute__((amdgpu_waves_per_eu(8)))
void seg_dice_main(const float* __restrict__ seg_feat,
                   const float* __restrict__ mask,
                   const int*   __restrict__ ind,
                   const float* __restrict__ target,
                   const uint32_t* __restrict__ wtab,
                   float* __restrict__ red_base) {
    const int bid   = blockIdx.x;
    const int b     = bid & 7;          // batch == XCD slot: seg+tgt slices stay in one L2
    const int t     = bid >> 3;         // 0..255 = ngrp*CHUNKS + chunk
    const int ngrp  = t >> 5;
    const int chunk = t & (CHUNKS - 1);
    const int tid   = threadIdx.x;

    const int p = chunk * PXB + (tid << 1);     // 2 consecutive px, same row

    // seg px-pair -> 8 f16x2 regs, once per block
    const float* seg_b = seg_feat + (size_t)b * Cc * HW;
    f16x2 sA[8];
    #pragma unroll
    for (int c = 0; c < 8; ++c) {
        const float2 v = *(const float2*)(seg_b + c * HW + p);
        sA[c] = pk(v.x, v.y);
    }
    const float xf = (float)(p & (Ww - 1)) * INV128;
    const float yf = (float)(p >> 7) * INV128;
    const f16x2 xq = pk(xf, xf + INV128);
    const f16x2 yq = pk(yf, yf);

    const int bnb = __builtin_amdgcn_readfirstlane(b * Nn + ngrp * GN);
    const f16x2 ZERO = {(__fp16)0.f, (__fp16)0.f};

    float inter = 0.f, ps = 0.f, ts = 0.f;

    #pragma unroll 1
    for (int n = 0; n < GN; ++n) {
        const int bn = bnb + n;

        const float2 t2 = *(const float2*)(target + (size_t)bn * HW + p);

        // uniform weight table -> SGPRs
        uint32_t wq[88];
        {
            const uint4* wt4 = (const uint4*)(wtab + bn * WSTRIDE);
            #pragma unroll
            for (int k = 0; k < 22; ++k) {
                const uint4 q = wt4[k];
                wq[4 * k + 0] = q.x; wq[4 * k + 1] = q.y;
                wq[4 * k + 2] = q.z; wq[4 * k + 3] = q.w;
            }
        }
        const float m  = mask[bn];
        const int   ib = ind[bn];

        const float x0 = (float)(ib & (Ww - 1)) * INV128;
        const float y0 = (float)(ib >> 7) * INV128;
        const f16x2 xr = xq - pk(x0, x0);   // exact k/128 arithmetic
        const f16x2 yr = yq - pk(y0, y0);

        // ---- layer 1: 10 -> 8, relu ----
        f16x2 h1[8];
        #pragma unroll
        for (int o = 0; o < 8; ++o) {
            const uint32_t wxy = wq[5 * o + 4];        // (w8, w9)
            f16x2 a = fma_lo4(wxy, xr, ZERO);          // w8*xr
            fma_hi(a, wxy, yr);                        // + w9*yr
            #pragma unroll
            for (int k = 0; k < 4; ++k) {
                const uint32_t w = wq[5 * o + k];      // (c2k, c2k+1)
                fma_lo(a, w, sA[2 * k]);
                fma_hi(a, w, sA[2 * k + 1]);
            }
            if (o & 1) add_hi(a, wq[76 + (o >> 1)]); else add_lo(a, wq[76 + (o >> 1)]);
            h1[o] = max2(a, ZERO);
        }

        // ---- layer 2: 8 -> 8, relu ----
        f16x2 h2[8];
        #pragma unroll
        for (int o = 0; o < 8; ++o) {
            const uint32_t w0 = wq[40 + 4 * o];
            f16x2 a = fma_lo4(w0, h1[0], ZERO);
            fma_hi(a, w0, h1[1]);
            #pragma unroll
            for (int k = 1; k < 4; ++k) {
                const uint32_t w = wq[40 + 4 * o + k];
                fma_lo(a, w, h1[2 * k]);
                fma_hi(a, w, h1[2 * k + 1]);
            }
            if (o & 1) add_hi(a, wq[80 + (o >> 1)]); else add_lo(a, wq[80 + (o >> 1)]);
            h2[o] = max2(a, ZERO);
        }

        // ---- layer 3: 8 -> 1, sigmoid + dice (f32) ----
        f16x2 z = fma_lo4(wq[72], h2[0], ZERO);
        fma_hi(z, wq[72], h2[1]);
        #pragma unroll
        for (int k = 1; k < 4; ++k) {
            const uint32_t w = wq[72 + k];
            fma_lo(z, w, h2[2 * k]);
            fma_hi(z, w, h2[2 * k + 1]);
        }
        add_lo(z, wq[84]);

        const float o0 = __builtin_amdgcn_rcpf(1.f + __expf(-(float)z.x));
        const float o1 = __builtin_amdgcn_rcpf(1.f + __expf(-(float)z.y));

        float in_ = o0 * t2.x;            in_ = fmaf(o1, t2.y, in_);
        float ps_ = o0 * o0;              ps_ = fmaf(o1, o1, ps_);
        float ts_ = t2.x * t2.x;          ts_ = fmaf(t2.y, t2.y, ts_);

        const float m2 = m * m;
        inter = fmaf(m2, in_, inter);
        ps    = fmaf(m2, ps_, ps);
        ts    = fmaf(m2, ts_, ts);
    }

    // wave reduce then cross-wave via LDS
    #pragma unroll
    for (int off = 32; off > 0; off >>= 1) {
        inter += __shfl_down(inter, off);
        ps    += __shfl_down(ps,    off);
        ts    += __shfl_down(ts,    off);
    }
    __shared__ float red[3][4];
    const int wave = tid >> 6;
    if ((tid & 63) == 0) { red[0][wave] = inter; red[1][wave] = ps; red[2][wave] = ts; }
    __syncthreads();
    if (tid == 0) {
        red_base[(b * 3 + 0) * SLOTS + t] = red[0][0] + red[0][1] + red[0][2] + red[0][3];
        red_base[(b * 3 + 1) * SLOTS + t] = red[1][0] + red[1][1] + red[1][2] + red[1][3];
        red_base[(b * 3 + 2) * SLOTS + t] = red[2][0] + red[2][1] + red[2][2] + red[2][3];
    }
}

// deterministic epilogue: 24 series (8 b x 3 comps) x 256 partials
__global__ void seg_dice_final(const float* __restrict__ red_base, float* __restrict__ out) {
    __shared__ float red[24][4];
    const int tid = threadIdx.x;  // 128 threads
    if (tid < 96) {
        const int series = tid >> 2;   // 0..23
        const int part   = tid & 3;    // 0..3
        const float4* p = (const float4*)(red_base + series * SLOTS + part * 64);
        float s = 0.f;
        #pragma unroll
        for (int i = 0; i < 16; ++i) { const float4 v = p[i]; s += (v.x + v.y) + (v.z + v.w); }
        red[series][part] = s;
    }
    __syncthreads();
    if (tid == 0) {
        float acc = 0.f;
        #pragma unroll
        for (int b = 0; b < Bb; ++b) {
            const float inter = red[b*3+0][0] + red[b*3+0][1] + red[b*3+0][2] + red[b*3+0][3];
            const float p2    = red[b*3+1][0] + red[b*3+1][1] + red[b*3+1][2] + red[b*3+1][3];
            const float t2    = red[b*3+2][0] + red[b*3+2][1] + red[b*3+2][2] + red[b*3+2][3];
            acc += 1.0f - (2.0f * inter + 1.0f) / (p2 + t2 + 1.0f);
        }
        out[0] = acc * (1.0f / (float)Bb);
    }
}

extern "C" void kernel_launch(void* const* d_in, const int* in_sizes, int n_in,
                              void* d_out, int out_size, void* d_ws, size_t ws_size,
                              hipStream_t stream) {
    const float* seg_feat    = (const float*)d_in[0];
    const float* conv_weight = (const float*)d_in[1];
    const float* mask        = (const float*)d_in[2];
    const int*   ind         = (const int*)d_in[3];
    const float* target      = (const float*)d_in[4];
    float* out = (float*)d_out;
    float* ws  = (float*)d_ws;

    uint32_t* wtab     = (uint32_t*)ws;
    float*    red_base = ws + RED_OFF;

    pack_weights<<<Bb * Nn, 96, 0, stream>>>(conv_weight, ind, wtab);
    seg_dice_main<<<NBLK, 256, 0, stream>>>(seg_feat, mask, ind, target, wtab, red_base);
    seg_dice_final<<<1, 128, 0, stream>>>(red_base, out);
}

// Round 14
// 38.640 us; speedup vs baseline: 1.1899x; 1.1899x over previous
//
#include <hip/hip_runtime.h>

#define Cc 8
#define Hh 128
#define Ww 128
#define Nn 64
#define Bb 8
#define Dd 169            // (C+2)*C + C + C*C + C + C + 1
#define HW (Hh * Ww)
#define NP 4              // n-pairs per block
#define NPG 8             // n-pair groups per batch (32/NP)
#define PXS 1024          // pixels per stripe (block)
#define NSTRIPE (HW / PXS)          // 16
#define NBLK (Bb * NPG * NSTRIPE)   // 1024 blocks
#define FRAGW 16                    // u32 per lane per n-pair in frag table
#define FRAG_U32 (256 * 64 * FRAGW) // 256 n-pairs total
#define SLOTS (NPG * NSTRIPE)       // 128 reduction slots per batch

#define INV128 (1.0f / 128.0f)

typedef __fp16 f16x2 __attribute__((ext_vector_type(2)));
typedef _Float16 h8 __attribute__((ext_vector_type(8)));
typedef float f32x4 __attribute__((ext_vector_type(4)));

static __device__ __forceinline__ uint32_t pku(float a, float b) {
    f16x2 t = __builtin_amdgcn_cvt_pkrtz(a, b);
    uint32_t u; __builtin_memcpy(&u, &t, 4); return u;
}
static __device__ __forceinline__ h8 u4h8(uint32_t a, uint32_t b, uint32_t c, uint32_t d) {
    uint32_t u[4] = {a, b, c, d}; h8 r; __builtin_memcpy(&r, u, 16); return r;
}

// ---- kernel A: build per-lane MFMA fragments for each n-pair ----
// One 64-lane wave per n-pair. M rows 0-7 = n0's MLP, 8-15 = n1's.
// Bijection (shared by A and B): L1 k = 8*g + e (g=lane>>4, e=0..7):
//   k 0-7 = seg channels, k8=x/128, k9=y/128, k10=1 (bias+x0/y0 fold), rest 0.
// L2 k2 = 4*g + e (e=0..3) = h1 D-layout rows; e>=4 zero. A2 block-diagonal.
// Slots/lane: [0..3]=A1 (8 f16), [4..5]=A2 (4 f16), [6..9]=w3slice f32,
//             [10..13]=C2(b2) f32, [14]=b3 f32, [15]=flag (m^2 on g=0,2)
__global__ void pack_frags(const float* __restrict__ conv_weight,
                           const float* __restrict__ mask,
                           const int*   __restrict__ ind,
                           uint32_t*    __restrict__ frag) {
    const int npair = blockIdx.x;            // 0..255
    const int b     = npair >> 5;
    const int bn0   = b * Nn + 2 * (npair & 31);
    const int l  = threadIdx.x;              // 0..63
    const int g  = l >> 4, r = l & 15, rr = r & 7;
    const int bnr = bn0 + (r >> 3);          // row-owner n
    const int bng = bn0 + (g >> 1);          // D-row-group owner n
    const float* base = conv_weight + (size_t)b * Dd * HW;
    const float* srcR = base + ind[bnr];
    const float* srcG = base + ind[bng];

    float a1[8];
    #pragma unroll
    for (int e = 0; e < 8; ++e) {
        const int k = 8 * g + e;
        float v = 0.f;
        if (k < 8)       v = srcR[(size_t)(rr * 10 + k) * HW];
        else if (k == 8) v = srcR[(size_t)(rr * 10 + 8) * HW];
        else if (k == 9) v = srcR[(size_t)(rr * 10 + 9) * HW];
        else if (k == 10) {
            const float w8 = srcR[(size_t)(rr * 10 + 8) * HW];
            const float w9 = srcR[(size_t)(rr * 10 + 9) * HW];
            const float b1 = srcR[(size_t)(80 + rr) * HW];
            const int   ib = ind[bnr];
            v = b1 - w8 * ((float)(ib & 127) * INV128)
                   - w9 * ((float)(ib >> 7) * INV128);
        }
        a1[e] = v;
    }
    float a2[4];
    #pragma unroll
    for (int e = 0; e < 4; ++e) {
        const int k2 = 4 * g + e;
        float v = 0.f;
        if (r < 8)  { if (k2 < 8)  v = srcR[(size_t)(88 + rr * 8 + k2) * HW]; }
        else        { if (k2 >= 8) v = srcR[(size_t)(88 + rr * 8 + (k2 - 8)) * HW]; }
        a2[e] = v;
    }
    float w3v[4], c2v[4];
    #pragma unroll
    for (int j = 0; j < 4; ++j) {
        const int c = (4 * g + j) & 7;
        w3v[j] = srcG[(size_t)(160 + c) * HW];
        c2v[j] = srcG[(size_t)(152 + c) * HW];
    }
    const float b3 = srcG[(size_t)168 * HW];
    const float mm = mask[bng];
    const float fl = (g == 0 || g == 2) ? mm * mm : 0.f;

    uint32_t* dst = frag + ((size_t)npair * 64 + l) * FRAGW;
    dst[0] = pku(a1[0], a1[1]); dst[1] = pku(a1[2], a1[3]);
    dst[2] = pku(a1[4], a1[5]); dst[3] = pku(a1[6], a1[7]);
    dst[4] = pku(a2[0], a2[1]); dst[5] = pku(a2[2], a2[3]);
    float* df = (float*)dst;
    df[6] = w3v[0]; df[7] = w3v[1]; df[8] = w3v[2]; df[9] = w3v[3];
    df[10] = c2v[0]; df[11] = c2v[1]; df[12] = c2v[2]; df[13] = c2v[3];
    df[14] = b3; df[15] = fl;
}

// ---- kernel B: MFMA main ----
__global__ __launch_bounds__(256)
void seg_dice_main(const float* __restrict__ seg_feat,
                   const float* __restrict__ target,
                   const uint32_t* __restrict__ frag,
                   float* __restrict__ red_base) {
    const int bid    = blockIdx.x;
    const int b      = bid & 7;
    const int rest   = bid >> 3;           // 0..127
    const int npg    = rest & 7;
    const int stripe = rest >> 3;          // 0..15
    const int p0     = stripe * PXS;
    const int tid  = threadIdx.x;
    const int wave = tid >> 6;
    const int l    = tid & 63;
    const int g    = l >> 4, col = l & 15;

    __shared__ uint4 lds4[PXS];            // pixel-major seg tile: 8 f16/px

    // stage seg stripe (f32 coalesced -> f16 px-major LDS)
    const float* seg_b = seg_feat + (size_t)b * Cc * HW;
    #pragma unroll
    for (int q = 0; q < 4; ++q) {
        const int px = q * 256 + tid;
        float v[8];
        #pragma unroll
        for (int c = 0; c < 8; ++c) v[c] = seg_b[(size_t)c * HW + p0 + px];
        lds4[px] = uint4{pku(v[0], v[1]), pku(v[2], v[3]),
                         pku(v[4], v[5]), pku(v[6], v[7])};
    }

    // load per-lane fragments for NP n-pairs
    const int npair0 = b * 32 + npg * NP;
    uint32_t A1u[NP][4], A2u[NP][2];
    float w3v[NP][4], c2v[NP][4], b3v[NP], flv[NP];
    int bnl[NP];
    #pragma unroll
    for (int j = 0; j < NP; ++j) {
        const uint4* fp = (const uint4*)(frag + ((size_t)(npair0 + j) * 64 + l) * FRAGW);
        const uint4 q0 = fp[0], q1 = fp[1], q2 = fp[2], q3 = fp[3];
        A1u[j][0] = q0.x; A1u[j][1] = q0.y; A1u[j][2] = q0.z; A1u[j][3] = q0.w;
        A2u[j][0] = q1.x; A2u[j][1] = q1.y;
        w3v[j][0] = __uint_as_float(q1.z); w3v[j][1] = __uint_as_float(q1.w);
        w3v[j][2] = __uint_as_float(q2.x); w3v[j][3] = __uint_as_float(q2.y);
        c2v[j][0] = __uint_as_float(q2.z); c2v[j][1] = __uint_as_float(q2.w);
        c2v[j][2] = __uint_as_float(q3.x); c2v[j][3] = __uint_as_float(q3.y);
        b3v[j] = __uint_as_float(q3.z);
        flv[j] = __uint_as_float(q3.w);
        bnl[j] = b * Nn + 2 * (npg * NP + j) + (l >> 5);
    }
    __syncthreads();

    const f32x4 ZF = {0.f, 0.f, 0.f, 0.f};
    float inter = 0.f, ps = 0.f, ts = 0.f;

    #pragma unroll 1
    for (int tt = wave; tt < PXS / 16; tt += 4) {
        const int pxt = tt * 16;
        const int pxg = p0 + pxt + col;

        // B1 fragment: g0 = seg ch 0-7 of this column; g1 = [x,y,1,0...]; g2,3 = 0
        const uint4 d = lds4[pxt + col];
        const uint32_t xv = pku((float)(pxg & 127) * INV128,
                                (float)(pxg >> 7) * INV128);
        const uint32_t ov = pku(1.f, 0.f);
        const uint32_t e0 = (g == 0) ? d.x : ((g == 1) ? xv : 0u);
        const uint32_t e1 = (g == 0) ? d.y : ((g == 1) ? ov : 0u);
        const uint32_t e2 = (g == 0) ? d.z : 0u;
        const uint32_t e3 = (g == 0) ? d.w : 0u;
        const h8 B1 = u4h8(e0, e1, e2, e3);

        #pragma unroll
        for (int j = 0; j < NP; ++j) {
            const h8 A1 = u4h8(A1u[j][0], A1u[j][1], A1u[j][2], A1u[j][3]);
            f32x4 h1 = __builtin_amdgcn_mfma_f32_16x16x32_f16(A1, B1, ZF, 0, 0, 0);
            h1[0] = fmaxf(h1[0], 0.f); h1[1] = fmaxf(h1[1], 0.f);
            h1[2] = fmaxf(h1[2], 0.f); h1[3] = fmaxf(h1[3], 0.f);

            const h8 B2 = u4h8(pku(h1[0], h1[1]), pku(h1[2], h1[3]), 0u, 0u);
            const h8 A2 = u4h8(A2u[j][0], A2u[j][1], 0u, 0u);
            f32x4 c2; c2[0] = c2v[j][0]; c2[1] = c2v[j][1];
                      c2[2] = c2v[j][2]; c2[3] = c2v[j][3];
            f32x4 h2 = __builtin_amdgcn_mfma_f32_16x16x32_f16(A2, B2, c2, 0, 0, 0);
            h2[0] = fmaxf(h2[0], 0.f); h2[1] = fmaxf(h2[1], 0.f);
            h2[2] = fmaxf(h2[2], 0.f); h2[3] = fmaxf(h2[3], 0.f);

            float zp = h2[0] * w3v[j][0];
            zp = fmaf(h2[1], w3v[j][1], zp);
            zp = fmaf(h2[2], w3v[j][2], zp);
            zp = fmaf(h2[3], w3v[j][3], zp);
            zp += __shfl_xor(zp, 16);
            const float z  = zp + b3v[j];
            const float o  = __builtin_amdgcn_rcpf(1.f + __expf(-z));
            const float tv = target[(size_t)bnl[j] * HW + pxg];
            const float fo = flv[j] * o;
            inter = fmaf(fo, tv, inter);
            ps    = fmaf(fo, o, ps);
            ts    = fmaf(flv[j], tv * tv, ts);
        }
    }

    // wave reduce then cross-wave
    #pragma unroll
    for (int off = 32; off > 0; off >>= 1) {
        inter += __shfl_down(inter, off);
        ps    += __shfl_down(ps,    off);
        ts    += __shfl_down(ts,    off);
    }
    __shared__ float red[3][4];
    if ((tid & 63) == 0) { red[0][wave] = inter; red[1][wave] = ps; red[2][wave] = ts; }
    __syncthreads();
    if (tid == 0) {
        red_base[(b * 3 + 0) * SLOTS + rest] = red[0][0] + red[0][1] + red[0][2] + red[0][3];
        red_base[(b * 3 + 1) * SLOTS + rest] = red[1][0] + red[1][1] + red[1][2] + red[1][3];
        red_base[(b * 3 + 2) * SLOTS + rest] = red[2][0] + red[2][1] + red[2][2] + red[2][3];
    }
}

// deterministic epilogue: 24 series x 128 partials
__global__ void seg_dice_final(const float* __restrict__ red_base, float* __restrict__ out) {
    __shared__ float red[24][4];
    const int tid = threadIdx.x;  // 128 threads
    if (tid < 96) {
        const int series = tid >> 2;
        const int part   = tid & 3;
        const float4* p = (const float4*)(red_base + series * SLOTS + part * 32);
        float s = 0.f;
        #pragma unroll
        for (int i = 0; i < 8; ++i) { const float4 v = p[i]; s += (v.x + v.y) + (v.z + v.w); }
        red[series][part] = s;
    }
    __syncthreads();
    if (tid == 0) {
        float acc = 0.f;
        #pragma unroll
        for (int b = 0; b < Bb; ++b) {
            const float inter = red[b*3+0][0] + red[b*3+0][1] + red[b*3+0][2] + red[b*3+0][3];
            const float p2    = red[b*3+1][0] + red[b*3+1][1] + red[b*3+1][2] + red[b*3+1][3];
            const float t2    = red[b*3+2][0] + red[b*3+2][1] + red[b*3+2][2] + red[b*3+2][3];
            acc += 1.0f - (2.0f * inter + 1.0f) / (p2 + t2 + 1.0f);
        }
        out[0] = acc * (1.0f / (float)Bb);
    }
}

extern "C" void kernel_launch(void* const* d_in, const int* in_sizes, int n_in,
                              void* d_out, int out_size, void* d_ws, size_t ws_size,
                              hipStream_t stream) {
    const float* seg_feat    = (const float*)d_in[0];
    const float* conv_weight = (const float*)d_in[1];
    const float* mask        = (const float*)d_in[2];
    const int*   ind         = (const int*)d_in[3];
    const float* target      = (const float*)d_in[4];
    float* out = (float*)d_out;

    uint32_t* fragtab  = (uint32_t*)d_ws;
    float*    red_base = (float*)d_ws + FRAG_U32;

    pack_frags<<<256, 64, 0, stream>>>(conv_weight, mask, ind, fragtab);
    seg_dice_main<<<NBLK, 256, 0, stream>>>(seg_feat, target, fragtab, red_base);
    seg_dice_final<<<1, 128, 0, stream>>>(red_base, out);
}